// Round 1
// 871.782 us; speedup vs baseline: 1.3455x; 1.3455x over previous
//
#include <hip/hip_runtime.h>
#include <cstdint>
#include <cstddef>

#define TT 256
#define NN 4096
#define CC 12
#define DD 256
#define KD 12
#define NB 16
#define NTH 512
#define HS 264   // halfs per h row: 256 + 8 pad (rows 16B-aligned)
#define XS 40    // halfs per x row: 32 + 8 pad

typedef _Float16 half8 __attribute__((ext_vector_type(8)));
typedef float f32x4 __attribute__((ext_vector_type(4)));
#define MFMA __builtin_amdgcn_mfma_f32_16x16x32_f16

struct FalseC { static constexpr bool value = false; };
struct TrueC  { static constexpr bool value = true;  };

// LDS: 33,792 (h planes) + 10,240 (4 x slots) + 8,192 (y partials) + 64 (idx)
//    = 52,288 B  (wy fragments moved to registers)
struct alignas(16) SM {
  _Float16 hhi[2][NB][HS];   // h hi plane, double-buffered
  _Float16 hlo[2][NB][HS];   // h lo plane
  _Float16 xhi[4][NB][XS];   // x_t slots (4-deep for distance-2 prefetch)
  _Float16 xlo[4][NB][XS];
  float    part[8][64][4];   // decoder y partials: [src wave][lane][reg]
  int      idxbuf[16];       // per-row argmax broadcast
};

__device__ __forceinline__ void split8(const float* w, half8& hi, half8& lo) {
  #pragma unroll
  for (int j = 0; j < 8; ++j) {
    _Float16 h = (_Float16)w[j];
    hi[j] = h;
    lo[j] = (_Float16)(w[j] - (float)h);
  }
}

// Raw barrier: drain only LDS (lgkmcnt); leave global loads/stores in flight.
// sched_barrier(0) pins ordering (rule #18: builtin s_barrier is not a
// compiler memory fence on its own).
__device__ __forceinline__ void BAR() {
  asm volatile("s_waitcnt lgkmcnt(0)" ::: "memory");
  __builtin_amdgcn_s_barrier();
  __builtin_amdgcn_sched_barrier(0);
}

__global__ __launch_bounds__(NTH, 2)
void seq2seq_kernel(const float* __restrict__ x,
                    const float* __restrict__ enc_Wx,
                    const float* __restrict__ enc_bx,
                    const float* __restrict__ enc_Wh,
                    const float* __restrict__ dec_Wx,
                    const float* __restrict__ dec_bx,
                    const float* __restrict__ dec_Wh,
                    const float* __restrict__ dec_Wy,
                    const float* __restrict__ dec_by,
                    float* __restrict__ out)
{
  __shared__ SM sm;
  const int tid  = (int)threadIdx.x;
  const int wid  = tid >> 6;
  const int lane = tid & 63;
  const int l15  = lane & 15;
  const int quad = lane >> 4;
  const int n0   = (int)blockIdx.x * NB;

  half8 Whi[2][8], Wlo[2][8];   // Wh B-fragments (AGPR-resident), persistent
  half8 Xhi[2], Xlo[2];         // Wx B-fragments (K=32 padded chunk)
  float bxr[2];
  // two prefetch register sets (x_{t+2} issued at step t, written at end of t+1)
  float pfA0 = 0.f, pfA1 = 0.f, pfA2 = 0.f;
  float pfB0 = 0.f, pfB1 = 0.f, pfB2 = 0.f;

  // earliest possible issue of x_1 (consumed at end of encoder step 0)
  if (wid == 1) {
    const float* xg = x + ((size_t)1 * NN + n0) * CC;
    pfB0 = xg[lane]; pfB1 = xg[lane + 64]; pfB2 = xg[lane + 128];
  }

  auto loadWh = [&](const float* __restrict__ W) {
    #pragma unroll
    for (int tt = 0; tt < 2; ++tt) {
      const int n = (wid * 2 + tt) * 16 + l15;
      #pragma unroll
      for (int c = 0; c < 8; ++c) {
        float w[8];
        const float* p = W + (size_t)n * DD + c * 32 + quad * 8;
        *(float4*)&w[0] = *(const float4*)p;
        *(float4*)&w[4] = *(const float4*)(p + 4);
        split8(w, Whi[tt][c], Wlo[tt][c]);
      }
    }
  };
  auto loadWx = [&](const float* __restrict__ Wx) {
    #pragma unroll
    for (int tt = 0; tt < 2; ++tt) {
      const int n = (wid * 2 + tt) * 16 + l15;
      float w[8];
      #pragma unroll
      for (int j = 0; j < 8; ++j) {
        const int k = quad * 8 + j;
        w[j] = (k < CC) ? Wx[(size_t)n * CC + k] : 0.f;
      }
      split8(w, Xhi[tt], Xlo[tt]);
    }
  };
  auto loadBx = [&](const float* __restrict__ bx) {
    #pragma unroll
    for (int tt = 0; tt < 2; ++tt) bxr[tt] = bx[(wid * 2 + tt) * 16 + l15];
  };

  // ---------------- init ----------------
  {
    unsigned* z;
    z = (unsigned*)&sm.hhi[0][0][0];
    for (int i = tid; i < NB * HS / 2; i += NTH) z[i] = 0u;
    z = (unsigned*)&sm.hlo[0][0][0];
    for (int i = tid; i < NB * HS / 2; i += NTH) z[i] = 0u;
    z = (unsigned*)&sm.xhi[0][0][0];
    for (int i = tid; i < 4 * NB * XS / 2; i += NTH) z[i] = 0u;
    z = (unsigned*)&sm.xlo[0][0][0];
    for (int i = tid; i < 4 * NB * XS / 2; i += NTH) z[i] = 0u;
  }
  loadWh(enc_Wh);
  loadWx(enc_Wx);
  loadBx(enc_bx);
  BAR();
  if (tid < NB * CC) {  // stage x_0 into slot 0
    const float v = x[(size_t)n0 * CC + tid];
    const _Float16 h = (_Float16)v;
    sm.xhi[0][tid / CC][tid % CC] = h;
    sm.xlo[0][tid / CC][tid % CC] = (_Float16)(v - (float)h);
  }
  BAR();

  // ---------------- encoder: 1 raw barrier/step, distance-2 prefetch ----------------
  auto encStep = [&](int t, auto IAc) {
    constexpr bool IA = decltype(IAc)::value;
    if (wid == 1) {  // issue x_{t+2} into set A (even t) / set B (odd t)
      const int tp = (t + 2 < TT) ? (t + 2) : (TT - 1);
      const float* xg = x + ((size_t)tp * NN + n0) * CC;
      if constexpr (IA) { pfA0 = xg[lane]; pfA1 = xg[lane + 64]; pfA2 = xg[lane + 128]; }
      else              { pfB0 = xg[lane]; pfB1 = xg[lane + 64]; pfB2 = xg[lane + 128]; }
    }
    const int rb = t & 1, wb = rb ^ 1, xs = t & 3;
    f32x4 aA0 = {0.f,0.f,0.f,0.f}, aA1 = {0.f,0.f,0.f,0.f};
    f32x4 aB0 = {0.f,0.f,0.f,0.f}, aB1 = {0.f,0.f,0.f,0.f};
    // x-term first: fills MFMA pipe while h reads stream in
    const half8 xh = *(const half8*)&sm.xhi[xs][l15][quad * 8];
    const half8 xl = *(const half8*)&sm.xlo[xs][l15][quad * 8];
    aA0 = MFMA(xh, Xhi[0], aA0, 0, 0, 0);
    aA1 = MFMA(xh, Xhi[1], aA1, 0, 0, 0);
    aB0 = MFMA(xl, Xhi[0], aB0, 0, 0, 0);
    aB1 = MFMA(xl, Xhi[1], aB1, 0, 0, 0);
    aB0 = MFMA(xh, Xlo[0], aB0, 0, 0, 0);
    aB1 = MFMA(xh, Xlo[1], aB1, 0, 0, 0);
    const _Float16* hh = &sm.hhi[rb][l15][0];
    const _Float16* hl = &sm.hlo[rb][l15][0];
    #pragma unroll
    for (int c = 0; c < 8; ++c) {
      const half8 ahi = *(const half8*)(hh + c * 32 + quad * 8);
      const half8 alo = *(const half8*)(hl + c * 32 + quad * 8);
      aA0 = MFMA(ahi, Whi[0][c], aA0, 0, 0, 0);
      aA1 = MFMA(ahi, Whi[1][c], aA1, 0, 0, 0);
      aB0 = MFMA(alo, Whi[0][c], aB0, 0, 0, 0);
      aB1 = MFMA(alo, Whi[1][c], aB1, 0, 0, 0);
      aA0 = MFMA(ahi, Wlo[0][c], aA0, 0, 0, 0);
      aA1 = MFMA(ahi, Wlo[1][c], aA1, 0, 0, 0);
    }
    #pragma unroll
    for (int r = 0; r < 4; ++r) {
      const int m = quad * 4 + r;
      const float v0 = fmaxf(aA0[r] + aB0[r] + bxr[0], 0.f);
      const float v1 = fmaxf(aA1[r] + aB1[r] + bxr[1], 0.f);
      const _Float16 h0 = (_Float16)v0, h1 = (_Float16)v1;
      sm.hhi[wb][m][(wid * 2 + 0) * 16 + l15] = h0;
      sm.hlo[wb][m][(wid * 2 + 0) * 16 + l15] = (_Float16)(v0 - (float)h0);
      sm.hhi[wb][m][(wid * 2 + 1) * 16 + l15] = h1;
      sm.hlo[wb][m][(wid * 2 + 1) * 16 + l15] = (_Float16)(v1 - (float)h1);
    }
    if (wid == 1) {  // write x_{t+1} (the OTHER set, issued one step ago)
      const int xw = (t + 1) & 3;
      float w0, w1, w2;
      if constexpr (IA) { w0 = pfB0; w1 = pfB1; w2 = pfB2; }
      else              { w0 = pfA0; w1 = pfA1; w2 = pfA2; }
      #pragma unroll
      for (int j = 0; j < 3; ++j) {
        const int i = lane + 64 * j;
        const float vv = (j == 0) ? w0 : (j == 1) ? w1 : w2;
        const _Float16 hx = (_Float16)vv;
        sm.xhi[xw][i / CC][i % CC] = hx;
        sm.xlo[xw][i / CC][i % CC] = (_Float16)(vv - (float)hx);
      }
    }
    BAR();
  };

  for (int t = 0; t < TT; t += 2) {
    encStep(t, TrueC{});
    encStep(t + 1, FalseC{});
  }
  // encoder final h now in planes[0]

  // ---------------- decoder setup ----------------
  loadWh(dec_Wh);
  loadWx(dec_Wx);
  loadBx(dec_bx);
  const float byv = (l15 < KD) ? dec_by[l15] : 0.f;
  half8 wyh, wyl;  // dec_Wy B-fragment for THIS wave's k-chunk (registers)
  {
    float w[8];
    if (l15 < KD) {
      const float* p = dec_Wy + (size_t)l15 * DD + wid * 32 + quad * 8;
      *(float4*)&w[0] = *(const float4*)p;
      *(float4*)&w[4] = *(const float4*)(p + 4);
    } else {
      #pragma unroll
      for (int j = 0; j < 8; ++j) w[j] = 0.f;
    }
    split8(w, wyh, wyl);
  }
  // sos one-hot A-fragment in registers: column CC-2 = 10
  half8 aX;
  #pragma unroll
  for (int j = 0; j < 8; ++j)
    aX[j] = (_Float16)((quad * 8 + j == CC - 2) ? 1.f : 0.f);

  // ---------------- decoder: 2 raw barriers/step, fully distributed y ----------------
  for (int t = 0; t < TT; ++t) {
    const int rb = t & 1, wb = rb ^ 1;
    f32x4 aA0 = {0.f,0.f,0.f,0.f}, aA1 = {0.f,0.f,0.f,0.f};
    f32x4 aB0 = {0.f,0.f,0.f,0.f}, aB1 = {0.f,0.f,0.f,0.f};
    // x-term from in-register one-hot sos (exact in f16 -> no lo A plane)
    aA0 = MFMA(aX, Xhi[0], aA0, 0, 0, 0);
    aA1 = MFMA(aX, Xhi[1], aA1, 0, 0, 0);
    aB0 = MFMA(aX, Xlo[0], aB0, 0, 0, 0);
    aB1 = MFMA(aX, Xlo[1], aB1, 0, 0, 0);
    const _Float16* hh = &sm.hhi[rb][l15][0];
    const _Float16* hl = &sm.hlo[rb][l15][0];
    #pragma unroll
    for (int c = 0; c < 8; ++c) {
      const half8 ahi = *(const half8*)(hh + c * 32 + quad * 8);
      const half8 alo = *(const half8*)(hl + c * 32 + quad * 8);
      aA0 = MFMA(ahi, Whi[0][c], aA0, 0, 0, 0);
      aA1 = MFMA(ahi, Whi[1][c], aA1, 0, 0, 0);
      aB0 = MFMA(alo, Whi[0][c], aB0, 0, 0, 0);
      aB1 = MFMA(alo, Whi[1][c], aB1, 0, 0, 0);
      aA0 = MFMA(ahi, Wlo[0][c], aA0, 0, 0, 0);
      aA1 = MFMA(ahi, Wlo[1][c], aA1, 0, 0, 0);
    }
    #pragma unroll
    for (int r = 0; r < 4; ++r) {
      const int m = quad * 4 + r;
      const float v0 = fmaxf(aA0[r] + aB0[r] + bxr[0], 0.f);
      const float v1 = fmaxf(aA1[r] + aB1[r] + bxr[1], 0.f);
      const _Float16 h0 = (_Float16)v0, h1 = (_Float16)v1;
      sm.hhi[wb][m][(wid * 2 + 0) * 16 + l15] = h0;
      sm.hlo[wb][m][(wid * 2 + 0) * 16 + l15] = (_Float16)(v0 - (float)h0);
      sm.hhi[wb][m][(wid * 2 + 1) * 16 + l15] = h1;
      sm.hlo[wb][m][(wid * 2 + 1) * 16 + l15] = (_Float16)(v1 - (float)h1);
    }
    // y-partial from OWN just-written 32-col slice (no cross-wave dependency):
    // wave w wrote cols [32w,32w+32) for all 16 rows == exactly k-chunk w of y.
    asm volatile("s_waitcnt lgkmcnt(0)" ::: "memory");  // own writes -> readable
    const half8 yh8 = *(const half8*)&sm.hhi[wb][l15][wid * 32 + quad * 8];
    const half8 yl8 = *(const half8*)&sm.hlo[wb][l15][wid * 32 + quad * 8];
    f32x4 yp = {0.f,0.f,0.f,0.f};
    yp = MFMA(yh8, wyh, yp, 0, 0, 0);
    yp = MFMA(yl8, wyh, yp, 0, 0, 0);
    yp = MFMA(yh8, wyl, yp, 0, 0, 0);
    *(f32x4*)&sm.part[wid][lane][0] = yp;
    BAR();  // h_t published + all 8 y-partials in LDS
    // row-split reduce: wave w owns rows 2w, 2w+1 (sh=lane>>5 duplicates halves)
    const int o  = l15;               // output class 0..15 (valid <12)
    const int rl = (lane >> 4) & 1;   // row-local
    const int sh = lane >> 5;         // source-half (partials 0-3 vs 4-7)
    const int m  = 2 * wid + rl;
    const int mq = m >> 2, mr = m & 3;
    const int pl = mq * 16 + o;       // lane index in partial C-layout for (m,o)
    float s0 = sm.part[4 * sh + 0][pl][mr] + sm.part[4 * sh + 1][pl][mr]
             + sm.part[4 * sh + 2][pl][mr] + sm.part[4 * sh + 3][pl][mr];
    s0 += __shfl_xor(s0, 32);         // combine the two source-halves
    const float yv = s0 + byv;
    if (sh == 0 && o < KD)
      out[((size_t)t * NN + n0 + m) * KD + o] = yv;  // fire-and-forget, never drained
    // argmax over o within each 16-lane group, first-max tie-break (np semantics)
    float v = (o < KD) ? yv : -1e30f;
    int io = o;
    #pragma unroll
    for (int d = 1; d < 16; d <<= 1) {
      const float ov = __shfl_xor(v, d);
      const int   oi = __shfl_xor(io, d);
      const bool take = (ov > v) || (ov == v && oi < io);
      v  = take ? ov : v;
      io = take ? oi : io;
    }
    if (sh == 0 && o == 0) sm.idxbuf[m] = io;
    BAR();  // idx published
    const int g = sm.idxbuf[l15];     // argmax for this lane's A-row
    #pragma unroll
    for (int j = 0; j < 8; ++j)
      aX[j] = (_Float16)((quad * 8 + j == g) ? 1.f : 0.f);
  }
}

extern "C" void kernel_launch(void* const* d_in, const int* in_sizes, int n_in,
                              void* d_out, int out_size, void* d_ws, size_t ws_size,
                              hipStream_t stream) {
  (void)in_sizes; (void)n_in; (void)d_ws; (void)ws_size; (void)out_size;
  const float* x      = (const float*)d_in[0];
  const float* enc_Wx = (const float*)d_in[1];
  const float* enc_bx = (const float*)d_in[2];
  const float* enc_Wh = (const float*)d_in[3];
  // d_in[4] enc_Wy, d_in[5] enc_by: computed-but-discarded in the reference
  const float* dec_Wx = (const float*)d_in[6];
  const float* dec_bx = (const float*)d_in[7];
  const float* dec_Wh = (const float*)d_in[8];
  const float* dec_Wy = (const float*)d_in[9];
  const float* dec_by = (const float*)d_in[10];
  float* outp = (float*)d_out;

  seq2seq_kernel<<<NN / NB, NTH, 0, stream>>>(
      x, enc_Wx, enc_bx, enc_Wh, dec_Wx, dec_bx, dec_Wh, dec_Wy, dec_by, outp);
}